// Round 1
// baseline (59.693 us; speedup 1.0000x reference)
//
#include <hip/hip_runtime.h>

namespace {
constexpr int Bn = 4, Dn = 4, Hn = 768, Wn = 768;
constexpr int HWc = Hn * Wn;                       // 589824
constexpr size_t DHWc = (size_t)Dn * HWc;          // 2359296
constexpr float BONUS = 10.0f;
}

__global__ __launch_bounds__(256) void cqi3d(const float* __restrict__ x,
                                             float* __restrict__ coords,
                                             float* __restrict__ ymax) {
#pragma clang fp contract(off)
    const int w = blockIdx.x * 256 + threadIdx.x;
    const int h = blockIdx.y;
    const int bd = blockIdx.z;
    const int d = bd & (Dn - 1);
    const int b = bd >> 2;

    const float* base = x + (size_t)b * DHWc;
    const int dm = d > 0 ? d - 1 : 0;
    const int dp = d < Dn - 1 ? d + 1 : Dn - 1;
    const int hm = h > 0 ? h - 1 : 0;
    const int hp = h < Hn - 1 ? h + 1 : Hn - 1;
    const int wm = w > 0 ? w - 1 : 0;
    const int wp = w < Wn - 1 ? w + 1 : Wn - 1;

    const int dz[3] = {dm, d, dp};
    const int hz[3] = {hm, h, hp};
    const int wz[3] = {wm, w, wp};

    float v[3][3][3];
#pragma unroll
    for (int a = 0; a < 3; ++a) {
        const float* pd = base + (size_t)dz[a] * HWc;
#pragma unroll
        for (int e = 0; e < 3; ++e) {
            const float* ph = pd + (size_t)hz[e] * Wn;
#pragma unroll
            for (int c = 0; c < 3; ++c) v[a][e][c] = ph[wz[c]];
        }
    }

    const float xc = v[1][1][1];

    // NMS: strictly greater than all 26 neighbours AND > 0 (m seeded at 0)
    float m = 0.0f;
#pragma unroll
    for (int a = 0; a < 3; ++a)
#pragma unroll
        for (int e = 0; e < 3; ++e)
#pragma unroll
            for (int c = 0; c < 3; ++c)
                if (!(a == 1 && e == 1 && c == 1)) m = fmaxf(m, v[a][e][c]);
    const bool nms = xc > m;

    // gradients / Hessian (kornia diff kernels, D-axis cross terms negated)
    const float gx  = 0.5f * (v[1][1][2] - v[1][1][0]);
    const float gy  = 0.5f * (v[1][2][1] - v[1][0][1]);
    const float gs  = 0.5f * (v[2][1][1] - v[0][1][1]);
    const float dxx = v[1][1][2] - 2.0f * xc + v[1][1][0];
    const float dyy = v[1][2][1] - 2.0f * xc + v[1][0][1];
    const float dss = v[2][1][1] - 2.0f * xc + v[0][1][1];
    const float dxy =  0.25f * (v[1][2][2] - v[1][2][0] - v[1][0][2] + v[1][0][0]);
    const float dys = -0.25f * (v[2][2][1] - v[2][0][1] - v[0][2][1] + v[0][0][1]);
    const float dxs = -0.25f * (v[2][1][2] - v[2][1][0] - v[0][1][2] + v[0][1][0]);

    // symmetric 3x3 Cramer solve H s = g
    const float cf00 = dyy * dss - dys * dys;
    const float cf01 = dxy * dss - dys * dxs;
    const float cf02 = dxy * dys - dyy * dxs;
    const float det  = dxx * cf00 - dxy * cf01 + dxs * cf02;
    const bool solved = fabsf(det) > 0.0f;
    const float sd = solved ? det : 1.0f;

    const float t0 = gy * dss - dys * gs;  // (r1*dss - dys*r2), reused verbatim
    const float sx = (gx * cf00 - dxy * t0 + dxs * (gy * dys - dyy * gs)) / sd;
    const float sy = (dxx * t0 - gx * cf01 + dxs * (dxy * gs - gy * dxs)) / sd;
    const float ss = (dxx * (dyy * gs - gy * dys) - dxy * (dxy * gs - gy * dxs) + gx * cf02) / sd;

    const bool valid = nms && solved;
    float dxv = valid ? -sx : 0.0f;
    float dyv = valid ? -sy : 0.0f;
    float dsv = valid ? -ss : 0.0f;
    const float mx = fmaxf(fmaxf(fabsf(dxv), fabsf(dyv)), fabsf(dsv));
    if (mx > 0.7f) { dxv = 0.0f; dyv = 0.0f; dsv = 0.0f; }

    const float dy_ = 0.5f * (gx * dxv + gy * dyv + gs * dsv);
    float y = xc + dy_;
    if (valid) y += BONUS;

    const size_t sp = (size_t)d * HWc + (size_t)h * Wn + (size_t)w;
    float* cb = coords + (size_t)b * 3 * DHWc;
    cb[sp]             = (float)d + dsv;  // channel 0: z (+dx_s)
    cb[DHWc + sp]      = (float)w + dxv;  // channel 1: x (+dx_x)
    cb[2 * DHWc + sp]  = (float)h + dyv;  // channel 2: y (+dx_y)
    ymax[(size_t)b * DHWc + sp] = y;
}

extern "C" void kernel_launch(void* const* d_in, const int* in_sizes, int n_in,
                              void* d_out, int out_size, void* d_ws, size_t ws_size,
                              hipStream_t stream) {
    const float* x = (const float*)d_in[0];
    float* out = (float*)d_out;
    float* coords = out;                          // (B,1,3,D,H,W) flat
    float* ymaxp  = out + (size_t)Bn * 3 * DHWc;  // (B,1,D,H,W) flat
    dim3 grid(Wn / 256, Hn, Bn * Dn);
    cqi3d<<<grid, dim3(256, 1, 1), 0, stream>>>(x, coords, ymaxp);
}